// Round 9
// baseline (174310.632 us; speedup 1.0000x reference)
//
#include <hip/hip_runtime.h>
#include <math.h>

// Invariant-EKF sequential scan, SINGLE WAVE, column-ownership + gap-filling.
// Round-8 post-mortem: ~82% stall with ~1000 VALU instr/step -> single-wave
// dependency latency + exposed LDS sync gaps dominate. This version fills
// every sync drain gap with independent register work (H after transpose#1
// writes, HPT after transpose#2 writes, Joseph's sHK-terms after sKK write)
// and deletes the sdx LDS round-trip (dxr recomputed from Ki broadcast).
// All arithmetic expression trees identical to the round-8 passing kernel.

#define GRAV 9.80665f
#define PIT 36   // LDS row pitch (floats) = 144B: 16B-aligned, gcd(36,32)=4
#define Q0c 0.001f
#define Q1c 0.01f

#define WSYNC() asm volatile("s_waitcnt lgkmcnt(0)" ::: "memory")

__device__ __forceinline__ float sel3f(int r, float a, float b, float c) {
    return (r == 0) ? a : ((r == 1) ? b : c);
}

__device__ __forceinline__ void m3mul_dev(const float* A, const float* B, float* C) {
#pragma unroll
    for (int i = 0; i < 3; ++i) {
#pragma unroll
        for (int j = 0; j < 3; ++j) {
            C[i*3+j] = A[i*3+0]*B[j] + A[i*3+1]*B[3+j] + A[i*3+2]*B[6+j];
        }
    }
}

__device__ __forceinline__ void so3exp_dev(float p0, float p1, float p2, float* R) {
    float sq = p0*p0 + p1*p1 + p2*p2;
    if (sq < 1e-16f) {
        R[0]=1.f;  R[1]=-p2;  R[2]=p1;
        R[3]=p2;   R[4]=1.f;  R[5]=-p0;
        R[6]=-p1;  R[7]=p0;   R[8]=1.f;
    } else {
        float ang = sqrtf(sq);
        float ax=p0/ang, ay=p1/ang, az=p2/ang;
        float s=sinf(ang), c=cosf(ang), o=1.f-c;
        R[0]=c+o*ax*ax;    R[1]=o*ax*ay-s*az; R[2]=o*ax*az+s*ay;
        R[3]=o*ay*ax+s*az; R[4]=c+o*ay*ay;    R[5]=o*ay*az-s*ax;
        R[6]=o*az*ax-s*ay; R[7]=o*az*ay+s*ax; R[8]=c+o*az*az;
    }
}

// lanes 0..32 write the 33 trajectory scalars for row NIDX
#define STORE_TRAJ(NIDX)                                                        \
    do {                                                                        \
        if (l < 33) {                                                           \
            float val = Rot[0];                                                 \
            if (l==1) val=Rot[1];  if (l==2) val=Rot[2];                        \
            if (l==3) val=Rot[3];  if (l==4) val=Rot[4];                        \
            if (l==5) val=Rot[5];  if (l==6) val=Rot[6];                        \
            if (l==7) val=Rot[7];  if (l==8) val=Rot[8];                        \
            if (l==9)  val=vv[0];  if (l==10) val=vv[1];  if (l==11) val=vv[2]; \
            if (l==12) val=pp[0];  if (l==13) val=pp[1];  if (l==14) val=pp[2]; \
            if (l==15) val=bw[0];  if (l==16) val=bw[1];  if (l==17) val=bw[2]; \
            if (l==18) val=ba[0];  if (l==19) val=ba[1];  if (l==20) val=ba[2]; \
            if (l==21) val=Rci[0]; if (l==22) val=Rci[1]; if (l==23) val=Rci[2];\
            if (l==24) val=Rci[3]; if (l==25) val=Rci[4]; if (l==26) val=Rci[5];\
            if (l==27) val=Rci[6]; if (l==28) val=Rci[7]; if (l==29) val=Rci[8];\
            if (l==30) val=tci[0]; if (l==31) val=tci[1]; if (l==32) val=tci[2];\
            out[ob + os_ * (NIDX) + orr] = val;                                 \
        }                                                                       \
    } while (0)

__global__ __launch_bounds__(64, 1)
void iekf_scan_kernel(const float* __restrict__ t,
                      const float* __restrict__ u,
                      const float* __restrict__ mc,
                      const float* __restrict__ v_mes,
                      const float* __restrict__ ang0,
                      float* __restrict__ out,
                      const int N)
{
    __shared__ __align__(16) float sT1[21*PIT];   // T1 row-major (transpose #1)
    __shared__ __align__(16) float sPT[21*PIT];   // Pn^T row-major (transpose #2)
    __shared__ __align__(16) float sHK[21*4];     // (hp0,hp1,ht0,ht1) per column
    __shared__ __align__(16) float sKK[21*4];     // (k0,k1,ks0,ks1) per column

    const int l = (int)threadIdx.x;
    const int jc = (l < 21) ? l : 20;   // owned column (clamped for idle lanes)
    const bool own = (l < 21);

    // ---- small state (replicated in all lanes) ----
    float Rot[9], vv[3], pp[3], bw[3], ba[3], Rci[9], tci[3];
    {
        const float roll = ang0[0], pitch = ang0[1], yaw = ang0[2];
        const float cr = cosf(roll),  srl = sinf(roll);
        const float cp = cosf(pitch), spt = sinf(pitch);
        const float cy = cosf(yaw),   syw = sinf(yaw);
        float rx[9] = {1.f,0.f,0.f, 0.f,cr,-srl, 0.f,srl,cr};
        float ry[9] = {cp,0.f,spt, 0.f,1.f,0.f, -spt,0.f,cp};
        float rz[9] = {cy,-syw,0.f, syw,cy,0.f, 0.f,0.f,1.f};
        float tm[9]; m3mul_dev(rz, ry, tm);
        m3mul_dev(tm, rx, Rot);
        vv[0]=v_mes[0]; vv[1]=v_mes[1]; vv[2]=v_mes[2];
#pragma unroll
        for (int c=0;c<3;c++){ pp[c]=0.f; bw[c]=0.f; ba[c]=0.f; tci[c]=0.f; }
        Rci[0]=1.f;Rci[1]=0.f;Rci[2]=0.f;Rci[3]=0.f;Rci[4]=1.f;Rci[5]=0.f;
        Rci[6]=0.f;Rci[7]=0.f;Rci[8]=1.f;
    }

    // ---- P column j in registers (P symmetric -> col == row) ----
    float Pcol[21];
#pragma unroll
    for (int i=0;i<21;i++){
        float pd = 0.f;
        if (i==0 || i==1)        pd = 0.001f;
        else if (i==3 || i==4)   pd = 0.1f;
        else if (i>=9  && i<12)  pd = 0.006f;
        else if (i>=12 && i<15)  pd = 0.004f;
        else if (i>=15 && i<18)  pd = 1e-6f;
        else if (i>=18)          pd = 0.005f;
        Pcol[i] = (own && i==jc) ? pd : 0.f;
    }

    // ---- output address constants ----
    int ob=0, os_=0, orr=0;
    if (l<33) {
        if (l<9)       { ob = 0;    os_ = 9; orr = l;    }
        else if (l<12) { ob = 9*N;  os_ = 3; orr = l-9;  }
        else if (l<15) { ob = 12*N; os_ = 3; orr = l-12; }
        else if (l<18) { ob = 15*N; os_ = 3; orr = l-15; }
        else if (l<21) { ob = 18*N; os_ = 3; orr = l-18; }
        else if (l<30) { ob = 21*N; os_ = 9; orr = l-21; }
        else           { ob = 30*N; os_ = 3; orr = l-30; }
    }

    STORE_TRAJ(0);

    float t_cur = t[0];

    // ---- software-pipelined inputs ----
    float tn_c = t[1];
    float uc0,uc1,uc2,uc3,uc4,uc5;
    { const float* un = u + 6; uc0=un[0]; uc1=un[1]; uc2=un[2]; uc3=un[3]; uc4=un[4]; uc5=un[5]; }
    float mcc0 = mc[2], mcc1 = mc[3];

    for (int n = 0; n < N-1; ++n) {
        const int np2 = (n+2 < N) ? (n+2) : (N-1);
        const float tn_n = t[np2];
        float un0,un1,un2,un3,un4,un5;
        { const float* un = u + (size_t)np2*6; un0=un[0]; un1=un[1]; un2=un[2]; un3=un[3]; un4=un[4]; un5=un[5]; }
        const float mcn0 = mc[2*np2], mcn1 = mc[2*np2+1];

        const float dt  = tn_c - t_cur;
        const float dt2 = dt*dt;
        const float u0=uc0,u1=uc1,u2=uc2,u3=uc3,u4=uc4,u5=uc5;
        const float mcv0=mcc0, mcv1=mcc1;

        // ========== stage A: state prop + M1/M2 (all lanes) ==========
        float Rot_n[9], v_n[3], p_n[3], om[3], M1[9], M2[9];
        om[0]=u0-bw[0]; om[1]=u1-bw[1]; om[2]=u2-bw[2];
        {
            const float ai0=u3-ba[0], ai1=u4-ba[1], ai2=u5-ba[2];
            const float ac0 = Rot[0]*ai0 + Rot[1]*ai1 + Rot[2]*ai2;
            const float ac1 = Rot[3]*ai0 + Rot[4]*ai1 + Rot[5]*ai2;
            const float ac2 = Rot[6]*ai0 + Rot[7]*ai1 + Rot[8]*ai2 - GRAV;
            v_n[0]=vv[0]+ac0*dt; v_n[1]=vv[1]+ac1*dt; v_n[2]=vv[2]+ac2*dt;
            p_n[0]=pp[0]+vv[0]*dt+0.5f*ac0*dt2;
            p_n[1]=pp[1]+vv[1]*dt+0.5f*ac1*dt2;
            p_n[2]=pp[2]+vv[2]*dt+0.5f*ac2*dt2;
            float E[9]; so3exp_dev(om[0]*dt, om[1]*dt, om[2]*dt, E);
            m3mul_dev(Rot, E, Rot_n);
        }
#pragma unroll
        for (int c=0;c<3;c++) {
            M1[0+c] = -vv[2]*Rot[3+c] + vv[1]*Rot[6+c];
            M1[3+c] =  vv[2]*Rot[0+c] - vv[0]*Rot[6+c];
            M1[6+c] = -vv[1]*Rot[0+c] + vv[0]*Rot[3+c];
            M2[0+c] = -pp[2]*Rot[3+c] + pp[1]*Rot[6+c];
            M2[3+c] =  pp[2]*Rot[0+c] - pp[0]*Rot[6+c];
            M2[6+c] = -pp[1]*Rot[0+c] + pp[0]*Rot[3+c];
        }
        const float hdt2 = 0.5f*dt2;
        const float sdt3 = dt*dt2*(1.0f/6.0f);
        const float dtg = dt*GRAV, hg = hdt2*GRAV;

        // ========== A = P + G Q G^T  (column j, registers only) ==========
        const int jb = jc/3, rj = jc - 3*jb;
        float mj0,mj1,mj2;
        {
            const float t0 = sel3f(rj,Rot[0],Rot[3],Rot[6]);
            const float t1 = sel3f(rj,Rot[1],Rot[4],Rot[7]);
            const float t2 = sel3f(rj,Rot[2],Rot[5],Rot[8]);
            const float a0 = sel3f(rj,M1[0],M1[3],M1[6]);
            const float a1 = sel3f(rj,M1[1],M1[4],M1[7]);
            const float a2 = sel3f(rj,M1[2],M1[5],M1[8]);
            const float b0 = sel3f(rj,M2[0],M2[3],M2[6]);
            const float b1 = sel3f(rj,M2[1],M2[4],M2[7]);
            const float b2 = sel3f(rj,M2[2],M2[5],M2[8]);
            mj0 = sel3f(jb, t0, a0, b0);
            mj1 = sel3f(jb, t1, a1, b1);
            mj2 = sel3f(jb, t2, a2, b2);
        }
        const bool jlt9 = (jc < 9);
        const bool jq1  = (jc >= 3 && jc < 6);
        const int  rq   = jc - 3;
        const float rjq0 = sel3f(rq,Rot[0],Rot[3],Rot[6]);
        const float rjq1 = sel3f(rq,Rot[1],Rot[4],Rot[7]);
        const float rjq2 = sel3f(rq,Rot[2],Rot[5],Rot[8]);

        float Acol[21];
#pragma unroll
        for (int i=0;i<21;i++){
            float W;
            if (i < 9) {
                const float mi0 = (i<3)?Rot[i*3+0] : (i<6)?M1[(i-3)*3+0] : M2[(i-6)*3+0];
                const float mi1 = (i<3)?Rot[i*3+1] : (i<6)?M1[(i-3)*3+1] : M2[(i-6)*3+1];
                const float mi2 = (i<3)?Rot[i*3+2] : (i<6)?M1[(i-3)*3+2] : M2[(i-6)*3+2];
                float w = dt2*Q0c*(mi0*mj0 + mi1*mj1 + mi2*mj2);
                if (i>=3 && i<6) {
                    const float ri0 = Rot[(i-3)*3+0], ri1 = Rot[(i-3)*3+1], ri2 = Rot[(i-3)*3+2];
                    const float w2 = w + dt2*Q1c*(ri0*rjq0 + ri1*rjq1 + ri2*rjq2);
                    w = jq1 ? w2 : w;
                }
                W = jlt9 ? w : 0.f;
            } else {
                const float qd = (i<12)?6e-9f : (i<15)?2e-4f : 1e-9f;
                W = (own && i==jc) ? dt2*qd : 0.f;
            }
            Acol[i] = Pcol[i] + W;
        }

        // ========== Phi row coefficients (uniform, all lanes) ==========
        float cbw[9][3], cba[9][3];
#pragma unroll
        for (int i=0;i<9;i++){
            const int br=i/3, r=i-3*br;
#pragma unroll
            for (int c=0;c<3;c++){
                const float m0r = (r==0)?Rot[c]:(r==1)?Rot[3+c]:Rot[6+c];
                const float m1r = (r==0)?M1[c]:(r==1)?M1[3+c]:M1[6+c];
                const float m2r = (r==0)?M2[c]:(r==1)?M2[3+c]:M2[6+c];
                const float sgm = (r==0)? GRAV*Rot[3+c] : (r==1)? -GRAV*Rot[0+c] : 0.f;
                cbw[i][c] = (br==0)? (-dt*m0r) : (br==1)? (-dt*m1r - hdt2*sgm)
                                               : (-dt*m2r - hdt2*m1r - sdt3*sgm);
                cba[i][c] = (br==0)? 0.f : (br==1)? (-dt*m0r) : (-hdt2*m0r);
            }
        }

        // ========== T1 = Phi @ A  (column j, registers only) ==========
        float T1col[21];
#pragma unroll
        for (int i=0;i<21;i++){
            if (i < 9) {
                const int br=i/3, r=i-3*br;
                const float ca0 = (br==1)? ((r==1)? -dtg:0.f) : (br==2)? ((r==1)? -hg:0.f) : 0.f;
                const float ca1 = (br==1)? ((r==0)?  dtg:0.f) : (br==2)? ((r==0)?  hg:0.f) : 0.f;
                const float cv0 = (br==2 && r==0)? dt : 0.f;
                const float cv1 = (br==2 && r==1)? dt : 0.f;
                const float cv2 = (br==2 && r==2)? dt : 0.f;
                float tv = Acol[i];
                tv += ca0*Acol[0];
                tv += ca1*Acol[1];
                tv += cv0*Acol[3];
                tv += cv1*Acol[4];
                tv += cv2*Acol[5];
                tv += cbw[i][0]*Acol[9];
                tv += cbw[i][1]*Acol[10];
                tv += cbw[i][2]*Acol[11];
                tv += cba[i][0]*Acol[12];
                tv += cba[i][1]*Acol[13];
                tv += cba[i][2]*Acol[14];
                T1col[i] = tv;
            } else {
                T1col[i] = Acol[i];
            }
        }

        // ========== transpose #1 writes: T1 columns -> rows ==========
        if (own) {
#pragma unroll
            for (int i=0;i<21;i++) sT1[i*PIT + l] = T1col[i];   // conflict-free
        }

        // ---- GAP 1: in-register H coefficients + residual (hides drain) ----
        float H0_3,H0_4,H0_5,H1_3,H1_4,H1_5,H0_9,H0_10,H0_11,H1_9,H1_10,H1_11;
        float H0_15,H0_16,H0_17,H1_15,H1_16,H1_17,H0_18,H0_19,H0_20,H1_18,H1_19,H1_20;
        float r0s, r1s;
        {
            float Rb[9]; m3mul_dev(Rot_n, Rci, Rb);
            const float vi0 = Rot_n[0]*v_n[0] + Rot_n[3]*v_n[1] + Rot_n[6]*v_n[2];
            const float vi1 = Rot_n[1]*v_n[0] + Rot_n[4]*v_n[1] + Rot_n[7]*v_n[2];
            const float vi2 = Rot_n[2]*v_n[0] + Rot_n[5]*v_n[1] + Rot_n[8]*v_n[2];
            H0_3 = Rb[1]; H0_4 = Rb[4]; H0_5 = Rb[7];
            H1_3 = Rb[2]; H1_4 = Rb[5]; H1_5 = Rb[8];
            H0_9 = tci[2]; H0_10 = 0.f; H0_11 = -tci[0];
            H1_9 = -tci[1]; H1_10 = tci[0]; H1_11 = 0.f;
            H0_15 =  Rci[4]*vi2 - Rci[7]*vi1;
            H0_16 = -Rci[1]*vi2 + Rci[7]*vi0;
            H0_17 =  Rci[1]*vi1 - Rci[4]*vi0;
            H1_15 =  Rci[5]*vi2 - Rci[8]*vi1;
            H1_16 = -Rci[2]*vi2 + Rci[8]*vi0;
            H1_17 =  Rci[2]*vi1 - Rci[5]*vi0;
            H0_18 = -om[2]; H0_19 = 0.f; H0_20 = om[0];
            H1_18 = om[1];  H1_19 = -om[0]; H1_20 = 0.f;
            const float vb1 = Rci[1]*vi0 + Rci[4]*vi1 + Rci[7]*vi2 + (tci[2]*om[0] - tci[0]*om[2]);
            const float vb2 = Rci[2]*vi0 + Rci[5]*vi1 + Rci[8]*vi2 + (tci[0]*om[1] - tci[1]*om[0]);
            r0s = -vb1; r1s = -vb2;
        }
        WSYNC();                               // (1) sT1 visible

        // ========== read T1 rows ==========
        float T1row[21];
        {
            const float* rp = &sT1[jc*PIT];
            const float4 a0 = *(const float4*)(rp+0);
            const float4 a1 = *(const float4*)(rp+4);
            const float4 a2 = *(const float4*)(rp+8);
            const float4 a3 = *(const float4*)(rp+12);
            const float4 a4 = *(const float4*)(rp+16);
            const float4 a5 = *(const float4*)(rp+20);
            T1row[0]=a0.x;  T1row[1]=a0.y;  T1row[2]=a0.z;  T1row[3]=a0.w;
            T1row[4]=a1.x;  T1row[5]=a1.y;  T1row[6]=a1.z;  T1row[7]=a1.w;
            T1row[8]=a2.x;  T1row[9]=a2.y;  T1row[10]=a2.z; T1row[11]=a2.w;
            T1row[12]=a3.x; T1row[13]=a3.y; T1row[14]=a3.z; T1row[15]=a3.w;
            T1row[16]=a4.x; T1row[17]=a4.y; T1row[18]=a4.z; T1row[19]=a4.w;
            T1row[20]=a5.x;
        }

        // ========== Pn = T1 @ Phi^T  (row j, registers only) ==========
        float Pnrow[21];
#pragma unroll
        for (int m=0;m<21;m++){
            if (m < 9) {
                const int br=m/3, r=m-3*br;
                const float ca0 = (br==1)? ((r==1)? -dtg:0.f) : (br==2)? ((r==1)? -hg:0.f) : 0.f;
                const float ca1 = (br==1)? ((r==0)?  dtg:0.f) : (br==2)? ((r==0)?  hg:0.f) : 0.f;
                const float cv0 = (br==2 && r==0)? dt : 0.f;
                const float cv1 = (br==2 && r==1)? dt : 0.f;
                const float cv2 = (br==2 && r==2)? dt : 0.f;
                float pv = T1row[m];
                pv += ca0*T1row[0];
                pv += ca1*T1row[1];
                pv += cv0*T1row[3];
                pv += cv1*T1row[4];
                pv += cv2*T1row[5];
                pv += cbw[m][0]*T1row[9];
                pv += cbw[m][1]*T1row[10];
                pv += cbw[m][2]*T1row[11];
                pv += cba[m][0]*T1row[12];
                pv += cba[m][1]*T1row[13];
                pv += cba[m][2]*T1row[14];
                Pnrow[m] = pv;
            } else {
                Pnrow[m] = T1row[m];
            }
        }

        // ========== transpose #2 writes: Pn rows -> columns ==========
        if (own) {
#pragma unroll
            for (int m=0;m<21;m++) sPT[m*PIT + l] = Pnrow[m];   // conflict-free
        }

        // ---- GAP 2: HPT dots (use Pnrow only; hides drain) ----
        float ht0=0.f, ht1=0.f;
        ht0 += H0_3*Pnrow[3];   ht0 += H0_4*Pnrow[4];   ht0 += H0_5*Pnrow[5];
        ht0 += H0_9*Pnrow[9];   ht0 += H0_10*Pnrow[10]; ht0 += H0_11*Pnrow[11];
        ht0 += H0_15*Pnrow[15]; ht0 += H0_16*Pnrow[16]; ht0 += H0_17*Pnrow[17];
        ht0 += H0_18*Pnrow[18]; ht0 += H0_19*Pnrow[19]; ht0 += H0_20*Pnrow[20];
        ht1 += H1_3*Pnrow[3];   ht1 += H1_4*Pnrow[4];   ht1 += H1_5*Pnrow[5];
        ht1 += H1_9*Pnrow[9];   ht1 += H1_10*Pnrow[10]; ht1 += H1_11*Pnrow[11];
        ht1 += H1_15*Pnrow[15]; ht1 += H1_16*Pnrow[16]; ht1 += H1_17*Pnrow[17];
        ht1 += H1_18*Pnrow[18]; ht1 += H1_19*Pnrow[19]; ht1 += H1_20*Pnrow[20];
        WSYNC();                               // (2) sPT visible

        // ========== read Pn columns ==========
        float Pncol[21];
        {
            const float* rp = &sPT[jc*PIT];
            const float4 a0 = *(const float4*)(rp+0);
            const float4 a1 = *(const float4*)(rp+4);
            const float4 a2 = *(const float4*)(rp+8);
            const float4 a3 = *(const float4*)(rp+12);
            const float4 a4 = *(const float4*)(rp+16);
            const float4 a5 = *(const float4*)(rp+20);
            Pncol[0]=a0.x;  Pncol[1]=a0.y;  Pncol[2]=a0.z;  Pncol[3]=a0.w;
            Pncol[4]=a1.x;  Pncol[5]=a1.y;  Pncol[6]=a1.z;  Pncol[7]=a1.w;
            Pncol[8]=a2.x;  Pncol[9]=a2.y;  Pncol[10]=a2.z; Pncol[11]=a2.w;
            Pncol[12]=a3.x; Pncol[13]=a3.y; Pncol[14]=a3.z; Pncol[15]=a3.w;
            Pncol[16]=a4.x; Pncol[17]=a4.y; Pncol[18]=a4.z; Pncol[19]=a4.w;
            Pncol[20]=a5.x;
        }

        // ========== HP dots (Pncol) + write sHK ==========
        float hp0=0.f, hp1=0.f;
        hp0 += H0_3*Pncol[3];   hp0 += H0_4*Pncol[4];   hp0 += H0_5*Pncol[5];
        hp0 += H0_9*Pncol[9];   hp0 += H0_10*Pncol[10]; hp0 += H0_11*Pncol[11];
        hp0 += H0_15*Pncol[15]; hp0 += H0_16*Pncol[16]; hp0 += H0_17*Pncol[17];
        hp0 += H0_18*Pncol[18]; hp0 += H0_19*Pncol[19]; hp0 += H0_20*Pncol[20];
        hp1 += H1_3*Pncol[3];   hp1 += H1_4*Pncol[4];   hp1 += H1_5*Pncol[5];
        hp1 += H1_9*Pncol[9];   hp1 += H1_10*Pncol[10]; hp1 += H1_11*Pncol[11];
        hp1 += H1_15*Pncol[15]; hp1 += H1_16*Pncol[16]; hp1 += H1_17*Pncol[17];
        hp1 += H1_18*Pncol[18]; hp1 += H1_19*Pncol[19]; hp1 += H1_20*Pncol[20];
        if (own) {
            float4 hk; hk.x=hp0; hk.y=hp1; hk.z=ht0; hk.w=ht1;
            *(float4*)&sHK[l*4] = hk;
        }
        WSYNC();                               // (3) sHK visible

        // ========== S (all lanes, broadcast reads) + solve + K (own col) ==========
        float x0, x1, ks0, ks1;
        {
            const float4 v3  = *(const float4*)&sHK[3*4];
            const float4 v4  = *(const float4*)&sHK[4*4];
            const float4 v5  = *(const float4*)&sHK[5*4];
            const float4 v9  = *(const float4*)&sHK[9*4];
            const float4 v10 = *(const float4*)&sHK[10*4];
            const float4 v11 = *(const float4*)&sHK[11*4];
            const float4 v15 = *(const float4*)&sHK[15*4];
            const float4 v16 = *(const float4*)&sHK[16*4];
            const float4 v17 = *(const float4*)&sHK[17*4];
            const float4 v18 = *(const float4*)&sHK[18*4];
            const float4 v19 = *(const float4*)&sHK[19*4];
            const float4 v20 = *(const float4*)&sHK[20*4];
            float S00 = 0.f, S01 = 0.f, S10 = 0.f, S11 = 0.f;
            S00 += v3.x*H0_3;  S00 += v4.x*H0_4;  S00 += v5.x*H0_5;
            S00 += v9.x*H0_9;  S00 += v10.x*H0_10; S00 += v11.x*H0_11;
            S00 += v15.x*H0_15; S00 += v16.x*H0_16; S00 += v17.x*H0_17;
            S00 += v18.x*H0_18; S00 += v19.x*H0_19; S00 += v20.x*H0_20;
            S01 += v3.x*H1_3;  S01 += v4.x*H1_4;  S01 += v5.x*H1_5;
            S01 += v9.x*H1_9;  S01 += v10.x*H1_10; S01 += v11.x*H1_11;
            S01 += v15.x*H1_15; S01 += v16.x*H1_16; S01 += v17.x*H1_17;
            S01 += v18.x*H1_18; S01 += v19.x*H1_19; S01 += v20.x*H1_20;
            S10 += v3.y*H0_3;  S10 += v4.y*H0_4;  S10 += v5.y*H0_5;
            S10 += v9.y*H0_9;  S10 += v10.y*H0_10; S10 += v11.y*H0_11;
            S10 += v15.y*H0_15; S10 += v16.y*H0_16; S10 += v17.y*H0_17;
            S10 += v18.y*H0_18; S10 += v19.y*H0_19; S10 += v20.y*H0_20;
            S11 += v3.y*H1_3;  S11 += v4.y*H1_4;  S11 += v5.y*H1_5;
            S11 += v9.y*H1_9;  S11 += v10.y*H1_10; S11 += v11.y*H1_11;
            S11 += v15.y*H1_15; S11 += v16.y*H1_16; S11 += v17.y*H1_17;
            S11 += v18.y*H1_18; S11 += v19.y*H1_19; S11 += v20.y*H1_20;
            S00 += mcv0; S11 += mcv1;
            const float b0 = ht0, b1 = ht1;
            if (fabsf(S00) >= fabsf(S10)) {        // LU partial pivot (ties keep row 0)
                const float fac = S10/S00;
                x1 = (b1 - fac*b0) / (S11 - fac*S01);
                x0 = (b0 - S01*x1) / S00;
            } else {
                const float fac = S00/S10;
                x1 = (b0 - fac*b1) / (S01 - fac*S11);
                x0 = (b1 - S11*x1) / S10;
            }
            ks0 = S00*x0 + S01*x1;
            ks1 = S10*x0 + S11*x1;
            if (own) {
                float4 kp; kp.x=x0; kp.y=x1; kp.z=ks0; kp.w=ks1;
                *(float4*)&sKK[l*4] = kp;
            }
        }

        // ---- GAP 4: Joseph's sHK-only terms (sHK synced at (3); hides sKK drain) ----
        float tA[21], tB[21];
#pragma unroll
        for (int i=0;i<21;i++){
            const float4 Hi = *(const float4*)&sHK[i*4];   // broadcast
            tA[i] = Hi.z*x0 + Hi.w*x1;
            tB[i] = x0*Hi.x + x1*Hi.y;
        }
        WSYNC();                               // (4) sKK visible

        // ========== Joseph update (both orientations) + dx ==========
        float dxr[21];
#pragma unroll
        for (int i=0;i<21;i++){
            const float4 Ki = *(const float4*)&sKK[i*4];   // broadcast
            const float puij = Pncol[i] - (Ki.x*hp0 + Ki.y*hp1) - tA[i]
                                        + (Ki.x*ks0 + Ki.y*ks1);
            const float puji = Pnrow[i] - tB[i] - (ht0*Ki.x + ht1*Ki.y)
                                        + (x0*Ki.z + x1*Ki.w);
            Pcol[i] = 0.5f*(puij + puji);
            dxr[i] = Ki.x*r0s + Ki.y*r1s;      // == x0_i*r0 + x1_i*r1, as before
        }

        // ========== state update (all lanes, uniform) ==========
        {
            float dR[9], Jm[9];
            const float q0 = dxr[0], q1 = dxr[1], q2 = dxr[2];
            const float sq = q0*q0 + q1*q1 + q2*q2;
            if (sq < 1e-16f) {
                dR[0]=1.f; dR[1]=-q2; dR[2]=q1;
                dR[3]=q2;  dR[4]=1.f; dR[5]=-q0;
                dR[6]=-q1; dR[7]=q0;  dR[8]=1.f;
                Jm[0]=1.f;      Jm[1]=-0.5f*q2; Jm[2]=0.5f*q1;
                Jm[3]=0.5f*q2;  Jm[4]=1.f;      Jm[5]=-0.5f*q0;
                Jm[6]=-0.5f*q1; Jm[7]=0.5f*q0;  Jm[8]=1.f;
            } else {
                const float ang = sqrtf(sq);
                const float ax=q0/ang, ay=q1/ang, az=q2/ang;
                const float s=sinf(ang), c=cosf(ang), o=1.f-c;
                dR[0]=c+o*ax*ax;    dR[1]=o*ax*ay-s*az; dR[2]=o*ax*az+s*ay;
                dR[3]=o*ay*ax+s*az; dR[4]=c+o*ay*ay;    dR[5]=o*ay*az-s*ax;
                dR[6]=o*az*ax-s*ay; dR[7]=o*az*ay+s*ax; dR[8]=c+o*az*az;
                const float sa  = s/ang;
                const float osa = 1.f - sa;
                const float tt  = o/ang;
                Jm[0]=sa+osa*ax*ax;    Jm[1]=osa*ax*ay-tt*az; Jm[2]=osa*ax*az+tt*ay;
                Jm[3]=osa*ay*ax+tt*az; Jm[4]=sa+osa*ay*ay;    Jm[5]=osa*ay*az-tt*ax;
                Jm[6]=osa*az*ax-tt*ay; Jm[7]=osa*az*ay+tt*ax; Jm[8]=sa+osa*az*az;
            }
            float nR[9]; m3mul_dev(dR, Rot_n, nR);
#pragma unroll
            for (int c=0;c<9;c++) Rot[c] = nR[c];
            const float dv0 = Jm[0]*dxr[3] + Jm[1]*dxr[4] + Jm[2]*dxr[5];
            const float dv1 = Jm[3]*dxr[3] + Jm[4]*dxr[4] + Jm[5]*dxr[5];
            const float dv2 = Jm[6]*dxr[3] + Jm[7]*dxr[4] + Jm[8]*dxr[5];
            const float dp0 = Jm[0]*dxr[6] + Jm[1]*dxr[7] + Jm[2]*dxr[8];
            const float dp1 = Jm[3]*dxr[6] + Jm[4]*dxr[7] + Jm[5]*dxr[8];
            const float dp2 = Jm[6]*dxr[6] + Jm[7]*dxr[7] + Jm[8]*dxr[8];
            const float nv0 = dR[0]*v_n[0] + dR[1]*v_n[1] + dR[2]*v_n[2] + dv0;
            const float nv1 = dR[3]*v_n[0] + dR[4]*v_n[1] + dR[5]*v_n[2] + dv1;
            const float nv2 = dR[6]*v_n[0] + dR[7]*v_n[1] + dR[8]*v_n[2] + dv2;
            const float np0 = dR[0]*p_n[0] + dR[1]*p_n[1] + dR[2]*p_n[2] + dp0;
            const float np1 = dR[3]*p_n[0] + dR[4]*p_n[1] + dR[5]*p_n[2] + dp1;
            const float np2v= dR[6]*p_n[0] + dR[7]*p_n[1] + dR[8]*p_n[2] + dp2;
            vv[0]=nv0; vv[1]=nv1; vv[2]=nv2;
            pp[0]=np0; pp[1]=np1; pp[2]=np2v;
            bw[0]+=dxr[9];  bw[1]+=dxr[10]; bw[2]+=dxr[11];
            ba[0]+=dxr[12]; ba[1]+=dxr[13]; ba[2]+=dxr[14];
            float E2[9]; so3exp_dev(dxr[15], dxr[16], dxr[17], E2);
            float nRc[9]; m3mul_dev(E2, Rci, nRc);
#pragma unroll
            for (int c=0;c<9;c++) Rci[c] = nRc[c];
            tci[0]+=dxr[18]; tci[1]+=dxr[19]; tci[2]+=dxr[20];
        }
        STORE_TRAJ(n+1);

        // ---- rotate software pipeline ----
        t_cur = tn_c;
        tn_c  = tn_n;
        uc0=un0; uc1=un1; uc2=un2; uc3=un3; uc4=un4; uc5=un5;
        mcc0=mcn0; mcc1=mcn1;
        // Single wave: DS pipe is in-order per wave, and the WSYNC memory
        // clobbers pin compiler ordering -> no trailing barrier needed.
    }
}

extern "C" void kernel_launch(void* const* d_in, const int* in_sizes, int n_in,
                              void* d_out, int out_size, void* d_ws, size_t ws_size,
                              hipStream_t stream) {
    const float* t     = (const float*)d_in[0];
    const float* u     = (const float*)d_in[1];
    const float* mc    = (const float*)d_in[2];
    const float* v_mes = (const float*)d_in[3];
    const float* ang0  = (const float*)d_in[5];
    float* out = (float*)d_out;
    const int N = in_sizes[0];
    (void)d_ws; (void)ws_size; (void)n_in; (void)out_size;
    iekf_scan_kernel<<<1, 64, 0, stream>>>(t, u, mc, v_mes, ang0, out, N);
}